// Round 8
// baseline (814.117 us; speedup 1.0000x reference)
//
#include <hip/hip_runtime.h>
#include <math.h>
#include <float.h>

#define BN_EPS 1e-5f
#define PBLK   8192      // edges per partition block
#define NBUCKP 832       // padded bucket count (scan width; N <= 106496)
#define ACAP   4096      // arena ints per 128-node bucket

typedef short s16x8 __attribute__((ext_vector_type(8)));
typedef float f32x4 __attribute__((ext_vector_type(4)));

__device__ __forceinline__ unsigned short f2bf(float f) {
    unsigned u = __float_as_uint(f);
    u += 0x7FFFu + ((u >> 16) & 1u);          // round-to-nearest-even
    return (unsigned short)(u >> 16);
}
__device__ __forceinline__ float bf2f(unsigned short b) {
    return __uint_as_float(((unsigned)b) << 16);
}

// ---------------------------------------------------------------------------
// Kernel A: prep + partition (R6/R3 staged version — best measured).
// 1024 blocks share the xb conversion and graph-boundary scan; blocks < EB
// partition edges (bucket = dst>>7).  val = (dst&127)<<17 | src  (N < 131072).
// ---------------------------------------------------------------------------
__global__ __launch_bounds__(512) void prep_partition(
    const float* __restrict__ x, unsigned short* __restrict__ xb,
    const float* __restrict__ W1, const float* __restrict__ W2,
    unsigned short* __restrict__ w1t, unsigned short* __restrict__ w2t,
    const int* __restrict__ src, const int* __restrict__ dst,
    const int* __restrict__ batch, int* __restrict__ gstart,
    int* __restrict__ bcur0, int* __restrict__ packed2,
    int N, int E, int EB, int G)
{
    __shared__ int hist[NBUCKP], lstart[NBUCKP], goff[NBUCKP], cur[NBUCKP];
    __shared__ int sorted[PBLK];
    __shared__ unsigned short sbkt[PBLK];

    int tid = threadIdx.x;
    int lane = tid & 63;
    int blk = blockIdx.x;

    // --- xb conversion (grid-strided over ALL blocks) ---
    int n4 = N * 16;
    for (int i = blk * 512 + tid; i < n4; i += gridDim.x * 512) {
        float4 f = *(const float4*)(x + (size_t)i * 4);
        ushort4 o;
        o.x = f2bf(f.x); o.y = f2bf(f.y); o.z = f2bf(f.z); o.w = f2bf(f.w);
        *(ushort4*)(xb + (size_t)i * 4) = o;
    }
    // --- graph segment boundaries (batch sorted): gstart[g] = first i with batch[i] >= g
    for (int i = blk * 512 + tid; i < N; i += gridDim.x * 512) {
        int bi = batch[i];
        int bp = (i == 0) ? -1 : batch[i - 1];
        for (int g = bp + 1; g <= bi; ++g) gstart[g] = i;
        if (i == N - 1)
            for (int g = bi + 1; g <= G; ++g) gstart[g] = N;
    }
    if (blk == 0)
        for (int idx = tid; idx < 4096; idx += 512)
            w1t[idx] = f2bf(W1[(idx & 63) * 64 + (idx >> 6)]);
    if (blk == 1)
        for (int idx = tid; idx < 4096; idx += 512)
            w2t[idx] = f2bf(W2[(idx & 63) * 64 + (idx >> 6)]);

    if (blk >= EB) return;

    // --- edge partition (blocks < EB only) ---
    int e0 = blk * PBLK;
    int cnt = E - e0; if (cnt > PBLK) cnt = PBLK; if (cnt < 0) cnt = 0;

    for (int i = tid; i < NBUCKP; i += 512) hist[i] = 0;
    __syncthreads();
    for (int i = tid; i < cnt; i += 512)
        atomicAdd(&hist[dst[e0 + i] >> 7], 1);
    __syncthreads();
    if (tid < 64) {
        int carry = 0;
        #pragma unroll
        for (int c = 0; c < NBUCKP / 64; ++c) {
            int idx = c * 64 + lane;
            int v = hist[idx];
            int xv = v;
            #pragma unroll
            for (int d = 1; d < 64; d <<= 1) {
                int t = __shfl_up(xv, d); if (lane >= d) xv += t;
            }
            lstart[idx] = xv - v + carry;
            carry += __shfl(xv, 63);
        }
    }
    __syncthreads();
    for (int i = tid; i < NBUCKP; i += 512) {
        cur[i] = lstart[i];
        if (hist[i] > 0) goff[i] = atomicAdd(&bcur0[i], hist[i]);
    }
    __syncthreads();
    for (int i = tid; i < cnt; i += 512) {
        int d = dst[e0 + i];
        int s = src[e0 + i];
        int b = d >> 7;
        int p = atomicAdd(&cur[b], 1);
        sorted[p] = ((d & 127) << 17) | s;
        sbkt[p] = (unsigned short)b;
    }
    __syncthreads();
    for (int i = tid; i < cnt; i += 512) {
        int b = sbkt[i];
        packed2[(size_t)b * ACAP + goff[b] + (i - lstart[b])] = sorted[i];
    }
}

// ---------------------------------------------------------------------------
// Kernel B: edge-parallel streaming accumulate + MFMA MLP.  NO sort phase.
// 512 thr = 8 waves, one block per 128-node bucket.
// vt = f32 [128][64] LDS tile (32KB), XOR-swizzled (byte ^= (row&7)<<5).
// Per edge: 1 readlane + 1 coalesced 128B xb-row load (lane = feature)
// + 1 ds_add_f32 (banks = lane%32 -> 2-way, free).  No cross-iteration
// dependencies: unroll 16 keeps 16 loads in flight per wave.
// ---------------------------------------------------------------------------
__global__ __launch_bounds__(512) void bucket_fused(
    const unsigned short* __restrict__ xb,
    const int* __restrict__ packed2, const int* __restrict__ bcur0,
    const unsigned short* __restrict__ w1t, const unsigned short* __restrict__ w2t,
    const float* __restrict__ b1, const float* __restrict__ b2,
    const float* __restrict__ Wg, const float* __restrict__ bg,
    unsigned short* __restrict__ h_out, float* __restrict__ gate_out, int N)
{
    __shared__ char vt_raw[32768];             // f32 [128][64], swizzled

    int tid = threadIdx.x;
    int lane = tid & 63;
    int wave = tid >> 6;                       // 0..7
    int b = blockIdx.x;
    int node0 = b * 128;
    int ecnt = bcur0[b];
    if (ecnt > ACAP) ecnt = ACAP;
    const int* arena = packed2 + (size_t)b * ACAP;

    // swizzled f32 accessor: row in [0,128), f in [0,64)
    auto vtp = [&](int row, int f) -> float* {
        return (float*)(vt_raw + row * 256 + (((unsigned)f * 4u) ^ (((unsigned)row & 7u) << 5)));
    };

    int rowbase = wave * 16;

    // ---- init: self terms (f32), wave-own rows ----
    for (int m = 0; m < 16; ++m) {
        int ln = rowbase + m;
        int node = node0 + ln;
        *vtp(ln, lane) = (node < N) ? bf2f(xb[(unsigned)node * 64u + lane]) : 0.f;
    }
    __syncthreads();

    // ---- edge-parallel accumulate: waves stream 64-edge batches ----
    for (int base = wave * 64; base < ecnt; base += 512) {
        int nb = ecnt - base; if (nb > 64) nb = 64;
        int ev = (base + lane < ecnt) ? arena[base + lane] : 0;   // coalesced
        if (nb == 64) {
            #pragma unroll 16
            for (int j = 0; j < 64; ++j) {
                int val = __builtin_amdgcn_readlane(ev, j);
                float f = bf2f(xb[(unsigned)(val & 0x1FFFF) * 64u + lane]);
                atomicAdd(vtp(val >> 17, lane), f);
            }
        } else {
            for (int j = 0; j < nb; ++j) {
                int val = __builtin_amdgcn_readlane(ev, j);
                float f = bf2f(xb[(unsigned)(val & 0x1FFFF) * 64u + lane]);
                atomicAdd(vtp(val >> 17, lane), f);
            }
        }
    }
    __syncthreads();

    // ---- MFMA MLP on own 16-row tile (f32 vt -> bf16 fragments) ----
    {
        int quad = lane >> 4;
        int col  = lane & 15;
        int arow = rowbase + col;

        // pack 8 consecutive f32 (32B-aligned, swizzle-contiguous) to bf16x8
        auto pack8 = [&](const float* p) -> s16x8 {
            f32x4 u = *(const f32x4*)p;
            f32x4 v = *(const f32x4*)(p + 4);
            s16x8 r;
            r[0] = (short)f2bf(u[0]); r[1] = (short)f2bf(u[1]);
            r[2] = (short)f2bf(u[2]); r[3] = (short)f2bf(u[3]);
            r[4] = (short)f2bf(v[0]); r[5] = (short)f2bf(v[1]);
            r[6] = (short)f2bf(v[2]); r[7] = (short)f2bf(v[3]);
            return r;
        };

        s16x8 a0 = pack8(vtp(arow, quad * 8));
        s16x8 a1 = pack8(vtp(arow, 32 + quad * 8));

        float b1v[4], b2v[4], wgv[4];
        #pragma unroll
        for (int nt = 0; nt < 4; ++nt) {
            b1v[nt] = b1[nt * 16 + col];
            b2v[nt] = b2[nt * 16 + col];
            wgv[nt] = Wg[nt * 16 + col];
        }
        float bgv = bg[0];

        f32x4 acc1[4];
        #pragma unroll
        for (int nt = 0; nt < 4; ++nt) {
            int off = (nt * 16 + col) * 64 + quad * 8;
            s16x8 w0 = *(const s16x8*)(w1t + off);
            s16x8 w1 = *(const s16x8*)(w1t + off + 32);
            f32x4 cc = {0.f, 0.f, 0.f, 0.f};
            cc = __builtin_amdgcn_mfma_f32_16x16x32_bf16(a0, w0, cc, 0, 0, 0);
            cc = __builtin_amdgcn_mfma_f32_16x16x32_bf16(a1, w1, cc, 0, 0, 0);
            acc1[nt] = cc;
        }
        // h1 = ReLU(acc1 + b1) stored back f32 IN PLACE (wave-own rows;
        // all fragment reads above complete before these writes: lockstep wave)
        #pragma unroll
        for (int nt = 0; nt < 4; ++nt)
            #pragma unroll
            for (int r = 0; r < 4; ++r) {
                float hv = fmaxf(acc1[nt][r] + b1v[nt], 0.f);
                *vtp(rowbase + quad * 4 + r, nt * 16 + col) = hv;
            }

        s16x8 g0 = pack8(vtp(arow, quad * 8));
        s16x8 g1 = pack8(vtp(arow, 32 + quad * 8));

        f32x4 acc2[4];
        #pragma unroll
        for (int nt = 0; nt < 4; ++nt) {
            int off = (nt * 16 + col) * 64 + quad * 8;
            s16x8 w0 = *(const s16x8*)(w2t + off);
            s16x8 w1 = *(const s16x8*)(w2t + off + 32);
            f32x4 cc = {0.f, 0.f, 0.f, 0.f};
            cc = __builtin_amdgcn_mfma_f32_16x16x32_bf16(g0, w0, cc, 0, 0, 0);
            cc = __builtin_amdgcn_mfma_f32_16x16x32_bf16(g1, w1, cc, 0, 0, 0);
            acc2[nt] = cc;
        }

        int nbase = node0 + rowbase;
        float gp[4] = {0.f, 0.f, 0.f, 0.f};
        #pragma unroll
        for (int nt = 0; nt < 4; ++nt)
            #pragma unroll
            for (int r = 0; r < 4; ++r) {
                float hv = fmaxf(acc2[nt][r] + b2v[nt], 0.f);
                int node = nbase + quad * 4 + r;
                if (node < N)
                    h_out[(size_t)node * 64 + nt * 16 + col] = f2bf(hv);
                gp[r] = fmaf(hv, wgv[nt], gp[r]);
            }
        #pragma unroll
        for (int r = 0; r < 4; ++r) {
            float t = gp[r];
            t += __shfl_xor(t, 1);
            t += __shfl_xor(t, 2);
            t += __shfl_xor(t, 4);
            t += __shfl_xor(t, 8);
            int node = nbase + quad * 4 + r;
            if (col == 0 && node < N) gate_out[node] = t + bgv;
        }
    }
}

// ---------------------------------------------------------------------------
// Kernel C: per-graph softmax-attention pooling + BN(eval) + linear + lsm.
// (R6 version — best measured.)  512 threads; online max+sum in one gate
// pass, then weighted h pass with 8-way wave split.
// ---------------------------------------------------------------------------
__global__ __launch_bounds__(512) void pool_final(
    const unsigned short* __restrict__ h, const float* __restrict__ gate,
    const int* __restrict__ gstart,
    const float* __restrict__ gamma_, const float* __restrict__ beta_,
    const float* __restrict__ mean_, const float* __restrict__ var_,
    const float* __restrict__ Wl, const float* __restrict__ bl,
    float* __restrict__ out)
{
    int g = blockIdx.x;
    int tid = threadIdx.x;

    int start = gstart[g];
    int end   = gstart[g + 1];

    __shared__ float red_m[8], red_s[8];
    __shared__ float pool_s[8 * 64];

    int lane = tid & 63;
    int wave = tid >> 6;

    // ---- one-pass online (max, sum-of-exp) over the gate segment ----
    float m = -FLT_MAX, s = 0.f;
    for (int i = start + tid; i < end; i += 512) {
        float gv = gate[i];
        if (gv > m) { s = s * __expf(m - gv) + 1.f; m = gv; }
        else        { s += __expf(gv - m); }
    }
    #pragma unroll
    for (int off = 32; off; off >>= 1) {
        float mo = __shfl_xor(m, off);
        float so = __shfl_xor(s, off);
        float mn = fmaxf(m, mo);
        s = s * __expf(m - mn) + so * __expf(mo - mn);
        m = mn;
    }
    if (lane == 0) { red_m[wave] = m; red_s[wave] = s; }
    __syncthreads();
    {
        float mn = red_m[0];
        #pragma unroll
        for (int w = 1; w < 8; ++w) mn = fmaxf(mn, red_m[w]);
        float ss = 0.f;
        #pragma unroll
        for (int w = 0; w < 8; ++w) ss += red_s[w] * __expf(red_m[w] - mn);
        m = mn; s = ss;
    }

    // ---- weighted h pass: 8 waves x 4 ILP ----
    float a0 = 0.f, a1 = 0.f, a2 = 0.f, a3 = 0.f;
    int i = start + wave;
    for (; i + 24 < end; i += 32) {
        float e0 = expf(gate[i]      - m);
        float e1 = expf(gate[i + 8]  - m);
        float e2 = expf(gate[i + 16] - m);
        float e3 = expf(gate[i + 24] - m);
        float t0 = bf2f(h[(size_t)(i)      * 64 + lane]);
        float t1 = bf2f(h[(size_t)(i + 8)  * 64 + lane]);
        float t2 = bf2f(h[(size_t)(i + 16) * 64 + lane]);
        float t3 = bf2f(h[(size_t)(i + 24) * 64 + lane]);
        a0 = fmaf(e0, t0, a0);
        a1 = fmaf(e1, t1, a1);
        a2 = fmaf(e2, t2, a2);
        a3 = fmaf(e3, t3, a3);
    }
    for (; i < end; i += 8) {
        float e = expf(gate[i] - m);
        a0 = fmaf(e, bf2f(h[(size_t)i * 64 + lane]), a0);
    }
    pool_s[wave * 64 + lane] = (a0 + a1) + (a2 + a3);
    __syncthreads();

    if (wave == 0) {
        float p = 0.f;
        #pragma unroll
        for (int w = 0; w < 8; ++w) p += pool_s[w * 64 + lane];
        p = (end > start) ? (p / s) : 0.f;
        float nrm = (p - mean_[lane]) / sqrtf(var_[lane] + BN_EPS) * gamma_[lane] + beta_[lane];
        float l0 = nrm * Wl[lane * 2 + 0];
        float l1 = nrm * Wl[lane * 2 + 1];
        #pragma unroll
        for (int off = 32; off; off >>= 1) {
            l0 += __shfl_xor(l0, off);
            l1 += __shfl_xor(l1, off);
        }
        if (lane == 0) {
            l0 += bl[0];
            l1 += bl[1];
            float mx = fmaxf(l0, l1);
            float lse = mx + logf(expf(l0 - mx) + expf(l1 - mx));
            out[g * 2 + 0] = l0 - lse;
            out[g * 2 + 1] = l1 - lse;
        }
    }
}

// ---------------------------------------------------------------------------
extern "C" void kernel_launch(void* const* d_in, const int* in_sizes, int n_in,
                              void* d_out, int out_size, void* d_ws, size_t ws_size,
                              hipStream_t stream)
{
    const float* x     = (const float*)d_in[0];
    const int*   eidx  = (const int*)d_in[1];   // [2, E]: row0=src, row1=dst
    const int*   batch = (const int*)d_in[2];
    const float* W1    = (const float*)d_in[3];
    const float* b1    = (const float*)d_in[4];
    const float* W2    = (const float*)d_in[5];
    const float* b2    = (const float*)d_in[6];
    const float* Wg    = (const float*)d_in[7];
    const float* bg    = (const float*)d_in[8];
    const float* bng   = (const float*)d_in[9];
    const float* bnb   = (const float*)d_in[10];
    const float* bnm   = (const float*)d_in[11];
    const float* bnv   = (const float*)d_in[12];
    const float* Wl    = (const float*)d_in[13];
    const float* bl    = (const float*)d_in[14];
    float* out = (float*)d_out;

    int N = in_sizes[0] / 64;        // requires N < 131072 (17-bit src pack)
    int E = in_sizes[1] / 2;
    int G = out_size / 2;
    int NP = ((N + 63) / 64) * 64;
    int NBUCK = (N + 127) / 128;     // 128-node arena buckets (<= NBUCKP)
    int EB = (E + PBLK - 1) / PBLK;
    int GRID_A = 1024 > EB ? 1024 : EB;

    char* w = (char*)d_ws;
    int* packed2 = (int*)w;                     w += (size_t)NBUCK * ACAP * 4;
    unsigned short* hxb  = (unsigned short*)w;  w += (size_t)NP * 64 * 2;   // xb
    float* gate  = (float*)w;                   w += ((size_t)N * 4 + 255) / 256 * 256;
    int* bcur0   = (int*)w;                     w += NBUCKP * 4;
    unsigned short* w1t = (unsigned short*)w;   w += 4096 * 2;
    unsigned short* w2t = (unsigned short*)w;   w += 4096 * 2;
    int* gstart  = (int*)w;                     w += ((size_t)(G + 1) * 4 + 255) / 256 * 256;
    unsigned short* hbuf = (unsigned short*)w;  // N*64 bf16 (dedicated h)

    const int* src = eidx;
    const int* dst = eidx + E;

    hipMemsetAsync(bcur0, 0, NBUCKP * sizeof(int), stream);

    prep_partition<<<GRID_A, 512, 0, stream>>>(x, hxb, W1, W2, w1t, w2t,
                                               src, dst, batch, gstart,
                                               bcur0, packed2,
                                               N, E, EB, G);

    bucket_fused  <<<NBUCK, 512, 0, stream>>>(hxb, packed2, bcur0, w1t, w2t,
                                              b1, b2, Wg, bg, hbuf, gate, N);

    pool_final    <<<G, 512, 0, stream>>>(hbuf, gate, gstart, bng, bnb, bnm, bnv,
                                          Wl, bl, out);
}

// Round 10
// 176.585 us; speedup vs baseline: 4.6103x; 4.6103x over previous
//
#include <hip/hip_runtime.h>
#include <math.h>
#include <float.h>

#define BN_EPS 1e-5f
#define PBLK   8192      // edges per partition block (= 512 thr * 16)
#define NBUCKP 832       // padded bucket count (scan width; N <= 106496)
#define ACAP   4096      // arena ints per 128-node bucket
#define STCAP  3072      // LDS stage capacity (bucket max ~2350)

typedef short s16x8 __attribute__((ext_vector_type(8)));
typedef float f32x4 __attribute__((ext_vector_type(4)));

__device__ __forceinline__ unsigned short f2bf(float f) {
    unsigned u = __float_as_uint(f);
    u += 0x7FFFu + ((u >> 16) & 1u);          // round-to-nearest-even
    return (unsigned short)(u >> 16);
}
__device__ __forceinline__ float bf2f(unsigned short b) {
    return __uint_as_float(((unsigned)b) << 16);
}
// XOR-swizzled byte offset into the 16KB vt tile: row in [0,128), byteoff in [0,128)
__device__ __forceinline__ int vtb(int row, int byteoff) {
    return row * 128 + (byteoff ^ ((row & 7) << 4));
}

// ---------------------------------------------------------------------------
// Kernel A: prep + partition, register-staged edges (single global read of
// src/dst).  1024 blocks share the xb conversion and graph-boundary scan;
// blocks < EB partition edges (bucket = dst>>7).
// val = (dst&127)<<17 | src  (requires N < 131072).
// ---------------------------------------------------------------------------
__global__ __launch_bounds__(512) void prep_partition(
    const float* __restrict__ x, unsigned short* __restrict__ xb,
    const float* __restrict__ W1, const float* __restrict__ W2,
    unsigned short* __restrict__ w1t, unsigned short* __restrict__ w2t,
    const int* __restrict__ src, const int* __restrict__ dst,
    const int* __restrict__ batch, int* __restrict__ gstart,
    int* __restrict__ bcur0, int* __restrict__ packed2,
    int N, int E, int EB, int G)
{
    __shared__ int hist[NBUCKP], lstart[NBUCKP], goff[NBUCKP], cur[NBUCKP];
    __shared__ int sorted[PBLK];
    __shared__ unsigned short sbkt[PBLK];

    int tid = threadIdx.x;
    int lane = tid & 63;
    int blk = blockIdx.x;

    // --- xb conversion (grid-strided over ALL blocks) ---
    int n4 = N * 16;
    for (int i = blk * 512 + tid; i < n4; i += gridDim.x * 512) {
        float4 f = *(const float4*)(x + (size_t)i * 4);
        ushort4 o;
        o.x = f2bf(f.x); o.y = f2bf(f.y); o.z = f2bf(f.z); o.w = f2bf(f.w);
        *(ushort4*)(xb + (size_t)i * 4) = o;
    }
    // --- graph segment boundaries (batch sorted): gstart[g] = first i with batch[i] >= g
    for (int i = blk * 512 + tid; i < N; i += gridDim.x * 512) {
        int bi = batch[i];
        int bp = (i == 0) ? -1 : batch[i - 1];
        for (int g = bp + 1; g <= bi; ++g) gstart[g] = i;
        if (i == N - 1)
            for (int g = bi + 1; g <= G; ++g) gstart[g] = N;
    }
    if (blk == 0)
        for (int idx = tid; idx < 4096; idx += 512)
            w1t[idx] = f2bf(W1[(idx & 63) * 64 + (idx >> 6)]);
    if (blk == 1)
        for (int idx = tid; idx < 4096; idx += 512)
            w2t[idx] = f2bf(W2[(idx & 63) * 64 + (idx >> 6)]);

    if (blk >= EB) return;

    // --- edge partition (blocks < EB only): single global read, reg-staged ---
    int e0 = blk * PBLK;
    int cnt = E - e0; if (cnt > PBLK) cnt = PBLK; if (cnt < 0) cnt = 0;

    for (int i = tid; i < NBUCKP; i += 512) hist[i] = 0;
    __syncthreads();

    int vv[16], bv[16];
    #pragma unroll
    for (int k = 0; k < 16; ++k) {
        int i = tid + k * 512;
        if (i < cnt) {
            int d = dst[e0 + i];
            int s = src[e0 + i];
            bv[k] = d >> 7;
            vv[k] = ((d & 127) << 17) | s;
            atomicAdd(&hist[bv[k]], 1);
        } else {
            bv[k] = -1;
            vv[k] = 0;
        }
    }
    __syncthreads();
    if (tid < 64) {
        int carry = 0;
        #pragma unroll
        for (int c = 0; c < NBUCKP / 64; ++c) {
            int idx = c * 64 + lane;
            int v = hist[idx];
            int xv = v;
            #pragma unroll
            for (int d = 1; d < 64; d <<= 1) {
                int t = __shfl_up(xv, d); if (lane >= d) xv += t;
            }
            lstart[idx] = xv - v + carry;
            carry += __shfl(xv, 63);
        }
    }
    __syncthreads();
    for (int i = tid; i < NBUCKP; i += 512) {
        cur[i] = lstart[i];
        if (hist[i] > 0) goff[i] = atomicAdd(&bcur0[i], hist[i]);
    }
    __syncthreads();
    #pragma unroll
    for (int k = 0; k < 16; ++k) {
        if (bv[k] >= 0) {
            int p = atomicAdd(&cur[bv[k]], 1);
            sorted[p] = vv[k];
            sbkt[p] = (unsigned short)bv[k];
        }
    }
    __syncthreads();
    for (int i = tid; i < cnt; i += 512) {
        int b = sbkt[i];
        packed2[(size_t)b * ACAP + goff[b] + (i - lstart[b])] = sorted[i];
    }
}

// ---------------------------------------------------------------------------
// Kernel B: fused per-bucket sort + PACKED bf16 gather + MFMA MLP (R7 version
// — best measured bucket: 53.4us).  512 thr = 8 waves, one block per
// 128-node bucket.  Gather: lane = (quarter q = lane>>4 -> edge slot,
// c = lane&15 -> 4-feature chunk); dwordx2 wave-load covers 4 source rows;
// 4-deep rung keeps 4 loads in flight (accumulation order == sequential).
// LDS = 16KB swizzled vt (hist/cur/excl aliased) + 12KB stage = 28.7KB.
// ---------------------------------------------------------------------------
__global__ __launch_bounds__(512) void bucket_fused(
    const unsigned short* __restrict__ xb,
    const int* __restrict__ packed2, const int* __restrict__ bcur0,
    const unsigned short* __restrict__ w1t, const unsigned short* __restrict__ w2t,
    const float* __restrict__ b1, const float* __restrict__ b2,
    const float* __restrict__ Wg, const float* __restrict__ bg,
    unsigned short* __restrict__ h_out, float* __restrict__ gate_out, int N)
{
    __shared__ char vt_raw[16384];             // vt[128][64] bf16, swizzled
    __shared__ int stage[STCAP];               // sorted src indices
    int* hist = (int*)vt_raw;                  // [128]   (alias: vt rows 0-3)
    int* cur  = hist + 128;                    // [128]   (alias: vt rows 4-7)
    int* excl = (int*)(vt_raw + 1024);         // [129]   (alias: vt rows 8-12)

    int tid = threadIdx.x;
    int lane = tid & 63;
    int wave = tid >> 6;                       // 0..7
    int b = blockIdx.x;
    int node0 = b * 128;
    int ecnt = bcur0[b];
    if (ecnt > ACAP) ecnt = ACAP;
    const int* arena = packed2 + (size_t)b * ACAP;

    // ---- phase 1: histogram ----
    if (tid < 128) hist[tid] = 0;
    __syncthreads();
    for (int i = tid; i < ecnt; i += 512)
        atomicAdd(&hist[arena[i] >> 17], 1);
    __syncthreads();

    // ---- exclusive scan over 128 buckets ----
    if (tid < 64) {
        int carry = 0;
        #pragma unroll
        for (int c = 0; c < 2; ++c) {
            int idx = c * 64 + lane;
            int v = hist[idx];
            int xv = v;
            #pragma unroll
            for (int d = 1; d < 64; d <<= 1) {
                int t = __shfl_up(xv, d); if (lane >= d) xv += t;
            }
            excl[idx] = xv - v + carry;
            cur[idx]  = xv - v + carry;
            carry += __shfl(xv, 63);
        }
        if (lane == 0) excl[128] = carry;
    }
    __syncthreads();

    // ---- scatter sorted src indices into the LDS stage ----
    for (int i = tid; i < ecnt; i += 512) {
        int v = arena[i];
        int p = atomicAdd(&cur[v >> 17], 1);
        if (p < STCAP) stage[p] = v & 0x1FFFF;
    }
    __syncthreads();

    // ---- pull excl boundaries into registers, then vt may alias over them ----
    int rowbase = wave * 16;
    int exv = excl[rowbase + (lane < 17 ? lane : 16)];
    if (exv > STCAP) exv = STCAP;
    __syncthreads();

    int q   = lane >> 4;               // edge slot within 4-edge group
    int c   = lane & 15;               // feature chunk: bf16 features 4c..4c+3
    int qsh = q << 2;                  // bpermute byte-index offset
    unsigned coff = (unsigned)(c * 4); // ushort offset of chunk within row

    // ---- phase 2: packed gather, 16 rows per wave ----
    for (int m = 0; m < 16; ++m) {
        int ln = rowbase + m;
        int node = node0 + ln;
        if (node < N) {
            int beg  = __builtin_amdgcn_readlane(exv, m);
            int end_ = __builtin_amdgcn_readlane(exv, m + 1);

            float a0 = 0.f, a1 = 0.f, a2 = 0.f, a3 = 0.f;

            for (int base = beg; base < end_; base += 64) {
                int eiv = (base + lane < end_) ? stage[base + lane] : 0;
                int deg = end_ - base; if (deg > 64) deg = 64;
                int kfull = deg >> 2;
                int k = 0;
                for (; k + 4 <= kfull; k += 4) {      // 16 edges, 4 loads in flight
                    int sA = __builtin_amdgcn_ds_bpermute(((k + 0) << 4) + qsh, eiv);
                    int sB = __builtin_amdgcn_ds_bpermute(((k + 1) << 4) + qsh, eiv);
                    int sC = __builtin_amdgcn_ds_bpermute(((k + 2) << 4) + qsh, eiv);
                    int sD = __builtin_amdgcn_ds_bpermute(((k + 3) << 4) + qsh, eiv);
                    uint2 dA = *(const uint2*)(xb + (unsigned)sA * 64u + coff);
                    uint2 dB = *(const uint2*)(xb + (unsigned)sB * 64u + coff);
                    uint2 dC = *(const uint2*)(xb + (unsigned)sC * 64u + coff);
                    uint2 dD = *(const uint2*)(xb + (unsigned)sD * 64u + coff);
                    a0 += __uint_as_float(dA.x << 16);
                    a1 += __uint_as_float(dA.x & 0xFFFF0000u);
                    a2 += __uint_as_float(dA.y << 16);
                    a3 += __uint_as_float(dA.y & 0xFFFF0000u);
                    a0 += __uint_as_float(dB.x << 16);
                    a1 += __uint_as_float(dB.x & 0xFFFF0000u);
                    a2 += __uint_as_float(dB.y << 16);
                    a3 += __uint_as_float(dB.y & 0xFFFF0000u);
                    a0 += __uint_as_float(dC.x << 16);
                    a1 += __uint_as_float(dC.x & 0xFFFF0000u);
                    a2 += __uint_as_float(dC.y << 16);
                    a3 += __uint_as_float(dC.y & 0xFFFF0000u);
                    a0 += __uint_as_float(dD.x << 16);
                    a1 += __uint_as_float(dD.x & 0xFFFF0000u);
                    a2 += __uint_as_float(dD.y << 16);
                    a3 += __uint_as_float(dD.y & 0xFFFF0000u);
                }
                for (; k + 2 <= kfull; k += 2) {      // 8 edges, 2 loads in flight
                    int sA = __builtin_amdgcn_ds_bpermute((k << 4) + qsh, eiv);
                    int sB = __builtin_amdgcn_ds_bpermute(((k + 1) << 4) + qsh, eiv);
                    uint2 dA = *(const uint2*)(xb + (unsigned)sA * 64u + coff);
                    uint2 dB = *(const uint2*)(xb + (unsigned)sB * 64u + coff);
                    a0 += __uint_as_float(dA.x << 16);
                    a1 += __uint_as_float(dA.x & 0xFFFF0000u);
                    a2 += __uint_as_float(dA.y << 16);
                    a3 += __uint_as_float(dA.y & 0xFFFF0000u);
                    a0 += __uint_as_float(dB.x << 16);
                    a1 += __uint_as_float(dB.x & 0xFFFF0000u);
                    a2 += __uint_as_float(dB.y << 16);
                    a3 += __uint_as_float(dB.y & 0xFFFF0000u);
                }
                for (; k < kfull; ++k) {              // 4 edges
                    int s = __builtin_amdgcn_ds_bpermute((k << 4) + qsh, eiv);
                    uint2 d = *(const uint2*)(xb + (unsigned)s * 64u + coff);
                    a0 += __uint_as_float(d.x << 16);
                    a1 += __uint_as_float(d.x & 0xFFFF0000u);
                    a2 += __uint_as_float(d.y << 16);
                    a3 += __uint_as_float(d.y & 0xFFFF0000u);
                }
                if (deg & 3) {                        // masked tail (<=3 edges)
                    int e  = (kfull << 2) + q;
                    int ec = (e < deg) ? e : (deg - 1);
                    int s  = __builtin_amdgcn_ds_bpermute(ec << 2, eiv);
                    float msk = (e < deg) ? 1.f : 0.f;
                    uint2 d = *(const uint2*)(xb + (unsigned)s * 64u + coff);
                    a0 = fmaf(__uint_as_float(d.x << 16),          msk, a0);
                    a1 = fmaf(__uint_as_float(d.x & 0xFFFF0000u),  msk, a1);
                    a2 = fmaf(__uint_as_float(d.y << 16),          msk, a2);
                    a3 = fmaf(__uint_as_float(d.y & 0xFFFF0000u),  msk, a3);
                }
            }
            // reduce across the 4 quarters (each holds a partial of chunk c)
            a0 += __shfl_xor(a0, 16); a1 += __shfl_xor(a1, 16);
            a2 += __shfl_xor(a2, 16); a3 += __shfl_xor(a3, 16);
            a0 += __shfl_xor(a0, 32); a1 += __shfl_xor(a1, 32);
            a2 += __shfl_xor(a2, 32); a3 += __shfl_xor(a3, 32);
            // self term
            uint2 sd = *(const uint2*)(xb + (unsigned)node * 64u + coff);
            a0 += __uint_as_float(sd.x << 16);
            a1 += __uint_as_float(sd.x & 0xFFFF0000u);
            a2 += __uint_as_float(sd.y << 16);
            a3 += __uint_as_float(sd.y & 0xFFFF0000u);
            // pack to bf16 and store the row chunk (quarter 0 only)
            if (q == 0) {
                unsigned lo = (unsigned)f2bf(a0) | ((unsigned)f2bf(a1) << 16);
                unsigned hi = (unsigned)f2bf(a2) | ((unsigned)f2bf(a3) << 16);
                uint2 pk = {lo, hi};
                *(uint2*)(vt_raw + vtb(ln, c * 8)) = pk;
            }
        } else if (q == 0) {
            uint2 z = {0u, 0u};
            *(uint2*)(vt_raw + vtb(ln, c * 8)) = z;
        }
    }
    // no barrier: phase 3 reads only this wave's own rows (same-wave DS order)

    // ---- phase 3: 16-node MFMA MLP on own tile ----
    {
        int quad = lane >> 4;
        int col  = lane & 15;

        s16x8 a0 = *(const s16x8*)(vt_raw + vtb(rowbase + col, quad * 16));
        s16x8 a1 = *(const s16x8*)(vt_raw + vtb(rowbase + col, 64 + quad * 16));

        float b1v[4], b2v[4], wgv[4];
        #pragma unroll
        for (int nt = 0; nt < 4; ++nt) {
            b1v[nt] = b1[nt * 16 + col];
            b2v[nt] = b2[nt * 16 + col];
            wgv[nt] = Wg[nt * 16 + col];
        }
        float bgv = bg[0];

        f32x4 acc1[4];
        #pragma unroll
        for (int nt = 0; nt < 4; ++nt) {
            int off = (nt * 16 + col) * 64 + quad * 8;
            s16x8 w0 = *(const s16x8*)(w1t + off);
            s16x8 w1 = *(const s16x8*)(w1t + off + 32);
            f32x4 cc = {0.f, 0.f, 0.f, 0.f};
            cc = __builtin_amdgcn_mfma_f32_16x16x32_bf16(a0, w0, cc, 0, 0, 0);
            cc = __builtin_amdgcn_mfma_f32_16x16x32_bf16(a1, w1, cc, 0, 0, 0);
            acc1[nt] = cc;
        }
        #pragma unroll
        for (int nt = 0; nt < 4; ++nt)
            #pragma unroll
            for (int r = 0; r < 4; ++r) {
                float hv = fmaxf(acc1[nt][r] + b1v[nt], 0.f);
                *(unsigned short*)(vt_raw + vtb(rowbase + quad * 4 + r, (nt * 16 + col) * 2)) = f2bf(hv);
            }

        s16x8 g0 = *(const s16x8*)(vt_raw + vtb(rowbase + col, quad * 16));
        s16x8 g1 = *(const s16x8*)(vt_raw + vtb(rowbase + col, 64 + quad * 16));

        f32x4 acc2[4];
        #pragma unroll
        for (int nt = 0; nt < 4; ++nt) {
            int off = (nt * 16 + col) * 64 + quad * 8;
            s16x8 w0 = *(const s16x8*)(w2t + off);
            s16x8 w1 = *(const s16x8*)(w2t + off + 32);
            f32x4 cc = {0.f, 0.f, 0.f, 0.f};
            cc = __builtin_amdgcn_mfma_f32_16x16x32_bf16(g0, w0, cc, 0, 0, 0);
            cc = __builtin_amdgcn_mfma_f32_16x16x32_bf16(g1, w1, cc, 0, 0, 0);
            acc2[nt] = cc;
        }

        int nbase = node0 + rowbase;
        float gp[4] = {0.f, 0.f, 0.f, 0.f};
        #pragma unroll
        for (int nt = 0; nt < 4; ++nt)
            #pragma unroll
            for (int r = 0; r < 4; ++r) {
                float hv = fmaxf(acc2[nt][r] + b2v[nt], 0.f);
                int node = nbase + quad * 4 + r;
                if (node < N)
                    h_out[(size_t)node * 64 + nt * 16 + col] = f2bf(hv);
                gp[r] = fmaf(hv, wgv[nt], gp[r]);
            }
        #pragma unroll
        for (int r = 0; r < 4; ++r) {
            float t = gp[r];
            t += __shfl_xor(t, 1);
            t += __shfl_xor(t, 2);
            t += __shfl_xor(t, 4);
            t += __shfl_xor(t, 8);
            int node = nbase + quad * 4 + r;
            if (col == 0 && node < N) gate_out[node] = t + bgv;
        }
    }
}

// ---------------------------------------------------------------------------
// Kernel C: per-graph softmax-attention pooling + BN(eval) + linear + lsm.
// (R6 version — best measured.)  512 threads; online max+sum in one gate
// pass, then weighted h pass with 8-way wave split.
// ---------------------------------------------------------------------------
__global__ __launch_bounds__(512) void pool_final(
    const unsigned short* __restrict__ h, const float* __restrict__ gate,
    const int* __restrict__ gstart,
    const float* __restrict__ gamma_, const float* __restrict__ beta_,
    const float* __restrict__ mean_, const float* __restrict__ var_,
    const float* __restrict__ Wl, const float* __restrict__ bl,
    float* __restrict__ out)
{
    int g = blockIdx.x;
    int tid = threadIdx.x;

    int start = gstart[g];
    int end   = gstart[g + 1];

    __shared__ float red_m[8], red_s[8];
    __shared__ float pool_s[8 * 64];

    int lane = tid & 63;
    int wave = tid >> 6;

    // ---- one-pass online (max, sum-of-exp) over the gate segment ----
    float m = -FLT_MAX, s = 0.f;
    for (int i = start + tid; i < end; i += 512) {
        float gv = gate[i];
        if (gv > m) { s = s * __expf(m - gv) + 1.f; m = gv; }
        else        { s += __expf(gv - m); }
    }
    #pragma unroll
    for (int off = 32; off; off >>= 1) {
        float mo = __shfl_xor(m, off);
        float so = __shfl_xor(s, off);
        float mn = fmaxf(m, mo);
        s = s * __expf(m - mn) + so * __expf(mo - mn);
        m = mn;
    }
    if (lane == 0) { red_m[wave] = m; red_s[wave] = s; }
    __syncthreads();
    {
        float mn = red_m[0];
        #pragma unroll
        for (int w = 1; w < 8; ++w) mn = fmaxf(mn, red_m[w]);
        float ss = 0.f;
        #pragma unroll
        for (int w = 0; w < 8; ++w) ss += red_s[w] * __expf(red_m[w] - mn);
        m = mn; s = ss;
    }

    // ---- weighted h pass: 8 waves x 4 ILP ----
    float a0 = 0.f, a1 = 0.f, a2 = 0.f, a3 = 0.f;
    int i = start + wave;
    for (; i + 24 < end; i += 32) {
        float e0 = expf(gate[i]      - m);
        float e1 = expf(gate[i + 8]  - m);
        float e2 = expf(gate[i + 16] - m);
        float e3 = expf(gate[i + 24] - m);
        float t0 = bf2f(h[(size_t)(i)      * 64 + lane]);
        float t1 = bf2f(h[(size_t)(i + 8)  * 64 + lane]);
        float t2 = bf2f(h[(size_t)(i + 16) * 64 + lane]);
        float t3 = bf2f(h[(size_t)(i + 24) * 64 + lane]);
        a0 = fmaf(e0, t0, a0);
        a1 = fmaf(e1, t1, a1);
        a2 = fmaf(e2, t2, a2);
        a3 = fmaf(e3, t3, a3);
    }
    for (; i < end; i += 8) {
        float e = expf(gate[i] - m);
        a0 = fmaf(e, bf2f(h[(size_t)i * 64 + lane]), a0);
    }
    pool_s[wave * 64 + lane] = (a0 + a1) + (a2 + a3);
    __syncthreads();

    if (wave == 0) {
        float p = 0.f;
        #pragma unroll
        for (int w = 0; w < 8; ++w) p += pool_s[w * 64 + lane];
        p = (end > start) ? (p / s) : 0.f;
        float nrm = (p - mean_[lane]) / sqrtf(var_[lane] + BN_EPS) * gamma_[lane] + beta_[lane];
        float l0 = nrm * Wl[lane * 2 + 0];
        float l1 = nrm * Wl[lane * 2 + 1];
        #pragma unroll
        for (int off = 32; off; off >>= 1) {
            l0 += __shfl_xor(l0, off);
            l1 += __shfl_xor(l1, off);
        }
        if (lane == 0) {
            l0 += bl[0];
            l1 += bl[1];
            float mx = fmaxf(l0, l1);
            float lse = mx + logf(expf(l0 - mx) + expf(l1 - mx));
            out[g * 2 + 0] = l0 - lse;
            out[g * 2 + 1] = l1 - lse;
        }
    }
}

// ---------------------------------------------------------------------------
extern "C" void kernel_launch(void* const* d_in, const int* in_sizes, int n_in,
                              void* d_out, int out_size, void* d_ws, size_t ws_size,
                              hipStream_t stream)
{
    const float* x     = (const float*)d_in[0];
    const int*   eidx  = (const int*)d_in[1];   // [2, E]: row0=src, row1=dst
    const int*   batch = (const int*)d_in[2];
    const float* W1    = (const float*)d_in[3];
    const float* b1    = (const float*)d_in[4];
    const float* W2    = (const float*)d_in[5];
    const float* b2    = (const float*)d_in[6];
    const float* Wg    = (const float*)d_in[7];
    const float* bg    = (const float*)d_in[8];
    const float* bng   = (const float*)d_in[9];
    const float* bnb   = (const float*)d_in[10];
    const float* bnm   = (const float*)d_in[11];
    const float* bnv   = (const float*)d_in[12];
    const float* Wl    = (const float*)d_in[13];
    const float* bl    = (const float*)d_in[14];
    float* out = (float*)d_out;

    int N = in_sizes[0] / 64;        // requires N < 131072 (17-bit src pack)
    int E = in_sizes[1] / 2;
    int G = out_size / 2;
    int NP = ((N + 63) / 64) * 64;
    int NBUCK = (N + 127) / 128;     // 128-node arena buckets (<= NBUCKP)
    int EB = (E + PBLK - 1) / PBLK;
    int GRID_A = 1024 > EB ? 1024 : EB;

    char* w = (char*)d_ws;
    int* packed2 = (int*)w;                     w += (size_t)NBUCK * ACAP * 4;
    unsigned short* hxb  = (unsigned short*)w;  w += (size_t)NP * 64 * 2;   // xb
    float* gate  = (float*)w;                   w += ((size_t)N * 4 + 255) / 256 * 256;
    int* bcur0   = (int*)w;                     w += NBUCKP * 4;
    unsigned short* w1t = (unsigned short*)w;   w += 4096 * 2;
    unsigned short* w2t = (unsigned short*)w;   w += 4096 * 2;
    int* gstart  = (int*)w;                     w += ((size_t)(G + 1) * 4 + 255) / 256 * 256;
    unsigned short* hbuf = (unsigned short*)w;  // N*64 bf16 (dedicated h)

    const int* src = eidx;
    const int* dst = eidx + E;

    hipMemsetAsync(bcur0, 0, NBUCKP * sizeof(int), stream);

    prep_partition<<<GRID_A, 512, 0, stream>>>(x, hxb, W1, W2, w1t, w2t,
                                               src, dst, batch, gstart,
                                               bcur0, packed2,
                                               N, E, EB, G);

    bucket_fused  <<<NBUCK, 512, 0, stream>>>(hxb, packed2, bcur0, w1t, w2t,
                                              b1, b2, Wg, bg, hbuf, gate, N);

    pool_final    <<<G, 512, 0, stream>>>(hbuf, gate, gstart, bng, bnb, bnm, bnv,
                                          Wl, bl, out);
}